// Round 10
// baseline (85.491 us; speedup 1.0000x reference)
//
#include <hip/hip_runtime.h>
#include <hip/hip_bf16.h>
#include <stdint.h>

// B=4, T=100, SP=20, S=2000, H=512, NH=8, D=64, CF=CB=4
// Token order space-major: s = sp*100 + t.  Internally q/k/v are permuted to
// time-major (pos = t*20 + sp) so the banded mask (|dt|<=4) becomes a
// contiguous key window of <=180 keys.  V stays time-major in global; the
// attention kernel stages its block's union V-window into LDS TRANSPOSED
// (pos-fast staging order -> conflict-free ds writes; global side L1-absorbed).
// GEMMs: BK=32, global_load_lds staging, 3-buffer depth-2 pipeline with
// COUNTED s_waitcnt (never 0 in the loop), XCD-chunked block swizzle.
// qkv: 128Mx128N @ 756 blocks (~3/CU); out: 64Mx128N @ 500 blocks (~2/CU).

typedef __bf16 bf16x8 __attribute__((ext_vector_type(8)));
typedef float f32x4 __attribute__((ext_vector_type(4)));

// ---- workspace layout (bytes, all 16B aligned) ----
static const size_t O_XB = 0;                  // bf16 x [8000][512]; reused as attn-out after qkv
static const size_t O_WT = 8192000;            // bf16 W^T x4, each [512 n][512 k]
static const size_t O_Q  = 10289152;           // bf16 q, time-major [4][8][2000][64] (pre-scaled by 1/8)
static const size_t O_K  = 18481152;           // bf16 k, time-major
static const size_t O_V  = 26673152;           // bf16 v, time-major [4][8][2000][64]
static const size_t O_RC = 34865152;           // f32 rope cos [100][32]
static const size_t O_RS = 34877952;           // f32 rope sin [100][32]

__device__ inline void gload16(const void* g, void* l) {
  __builtin_amdgcn_global_load_lds((const __attribute__((address_space(1))) void*)g,
                                   (__attribute__((address_space(3))) void*)l, 16, 0, 0);
}

// bijective XCD-chunk swizzle (m204)
__device__ inline int xcd_swz(int orig, int nwg) {
  const int q8 = nwg >> 3, r8 = nwg & 7;
  const int xcd = orig & 7;
  return (xcd < r8 ? xcd * (q8 + 1) : r8 * (q8 + 1) + (xcd - r8) * q8) + (orig >> 3);
}

// ---------------- P0: prep — x f32->bf16, LDS-tiled W transpose, rope ----------------
__global__ __launch_bounds__(256) void prep_kernel(
    const float* __restrict__ x, const float* __restrict__ Wq, const float* __restrict__ Wk,
    const float* __restrict__ Wv, const float* __restrict__ Wo,
    __bf16* __restrict__ xb, __bf16* __restrict__ wt,
    float* __restrict__ ropeC, float* __restrict__ ropeS)
{
  __shared__ float tile[64][65];
  const int tid = threadIdx.x;
  const int bx = blockIdx.x;
  if (bx < 4000) {                                     // x cvt: 1,024,000 float4s
    const int idx = bx * 256 + tid;
    float4 v = ((const float4*)x)[idx];
    union { ushort4 u; __bf16 b[4]; } p;
    p.b[0] = (__bf16)v.x; p.b[1] = (__bf16)v.y; p.b[2] = (__bf16)v.z; p.b[3] = (__bf16)v.w;
    ((ushort4*)xb)[idx] = p.u;
    return;
  }
  const int wb = bx - 4000;                            // 0..255: W transpose tiles
  const int mat = wb >> 6, sub = wb & 63;
  const int tk = (sub >> 3) * 64, tn = (sub & 7) * 64;
  const float* W = (mat == 0) ? Wq : (mat == 1) ? Wk : (mat == 2) ? Wv : Wo;
#pragma unroll
  for (int it = 0; it < 16; ++it) {                    // coalesced read: lanes span n
    const int idx = it * 256 + tid;
    const int kl = idx >> 6, nl = idx & 63;
    tile[kl][nl] = W[(size_t)(tk + kl) * 512 + tn + nl];
  }
  __syncthreads();
#pragma unroll
  for (int it = 0; it < 16; ++it) {                    // coalesced write: lanes span k
    const int idx = it * 256 + tid;
    const int nl = idx >> 6, kl = idx & 63;
    wt[(size_t)mat * 262144 + (size_t)(tn + nl) * 512 + tk + kl] = (__bf16)tile[kl][nl];
  }
  if (wb == 0) {                                       // rope tables [t][i]
    for (int idx = tid; idx < 3200; idx += 256) {
      const int t = idx >> 5, i = idx & 31;
      const float f = (float)t * powf(10000.0f, -(float)i / 32.0f);
      ropeC[idx] = cosf(f);
      ropeS[idx] = sinf(f);
    }
  }
}

// ---------------- GEMM: one 16-MFMA step from LDS buffers (128M tile) ----------------
__device__ inline void mfma_step(const __bf16* ab, const __bf16* bb,
                                 f32x4 (&acc)[4][4], int wm, int wn, int lr, int g)
{
  bf16x8 af[4], bfr[4];
#pragma unroll
  for (int f = 0; f < 4; ++f) {
    af[f]  = *(const bf16x8*)(ab + (wm + f * 16 + lr) * 32 + g * 8);
    bfr[f] = *(const bf16x8*)(bb + (wn + f * 16 + lr) * 32 + g * 8);
  }
#pragma unroll
  for (int i = 0; i < 4; ++i)
#pragma unroll
    for (int j = 0; j < 4; ++j)
      acc[i][j] = __builtin_amdgcn_mfma_f32_16x16x32_bf16(af[i], bfr[j], acc[i][j], 0, 0, 0);
}

// ---------------- GEMM core: C[128x128] = A[128x512]*B^T, BK=32, depth-2 counted ----------------
// As/Bs: 3 buffers x 4096 bf16.  Loads for K-step k+2 issued at iter k, waited
// (vmcnt(4)) at the END of iter k -> stage(k+1) complete, stage(k+2) in flight.
__device__ inline void gemm_core_p2(const __bf16* __restrict__ A, const __bf16* __restrict__ Bm,
                                    __bf16* As, __bf16* Bs, f32x4 (&acc)[4][4],
                                    int m0, int n0, int tid, int wm, int wn, int lr, int g)
{
  const int r0 = tid >> 2;          // staging row within half-tile (0..63)
  const int aq = tid & 3;           // 16B quad within 64B row
  int gm0 = m0 + r0;      if (gm0 > 7999) gm0 = 7999;   // clamp M edge (dup rows, stores guarded)
  int gm1 = m0 + r0 + 64; if (gm1 > 7999) gm1 = 7999;
  const __bf16* a0 = A + (size_t)gm0 * 512 + aq * 8;
  const __bf16* a1 = A + (size_t)gm1 * 512 + aq * 8;
  const __bf16* b0 = Bm + (size_t)(n0 + r0) * 512 + aq * 8;
  const __bf16* b1 = Bm + (size_t)(n0 + r0 + 64) * 512 + aq * 8;

#define STAGE_QK(J, BUF) do {                                      \
    gload16(a0 + (J) * 32, As + (BUF) * 4096 + tid * 8);           \
    gload16(a1 + (J) * 32, As + (BUF) * 4096 + tid * 8 + 2048);    \
    gload16(b0 + (J) * 32, Bs + (BUF) * 4096 + tid * 8);           \
    gload16(b1 + (J) * 32, Bs + (BUF) * 4096 + tid * 8 + 2048);    \
  } while (0)

  STAGE_QK(0, 0);
  STAGE_QK(1, 1);
  __syncthreads();                  // full drain once (also publishes posTbl)

  int cur = 0, st = 2;
  for (int k = 0; k < 14; ++k) {
    STAGE_QK(k + 2, st);
    mfma_step(As + cur * 4096, Bs + cur * 4096, acc, wm, wn, lr, g);
    asm volatile("s_waitcnt vmcnt(4)" ::: "memory");   // stage(k+1) done; stage(k+2) in flight
    __builtin_amdgcn_s_barrier();
    __builtin_amdgcn_sched_barrier(0);
    if (++cur == 3) cur = 0;
    if (++st == 3) st = 0;
  }
  // k = 14: cur == 2
  mfma_step(As + 2 * 4096, Bs + 2 * 4096, acc, wm, wn, lr, g);
  asm volatile("s_waitcnt vmcnt(0)" ::: "memory");     // drain stage(15)
  __builtin_amdgcn_s_barrier();
  __builtin_amdgcn_sched_barrier(0);
  // k = 15: buffer 0
  mfma_step(As, Bs, acc, wm, wn, lr, g);
#undef STAGE_QK
}

// ---------------- P1: QKV GEMM + bias + RoPE + time-major permute ----------------
// 1D grid 756, XCD-swizzled; wgid -> (mt, mat, nt) with A-panel sharers contiguous.
__global__ __launch_bounds__(256) void qkv_gemm(
    const __bf16* __restrict__ xb, const __bf16* __restrict__ wt,
    const float* __restrict__ bq, const float* __restrict__ bk, const float* __restrict__ bv,
    const float* __restrict__ ropeC, const float* __restrict__ ropeS,
    __bf16* __restrict__ qws, __bf16* __restrict__ kws, __bf16* __restrict__ vws)
{
  const int tid = threadIdx.x;
  const int wgid = xcd_swz(blockIdx.x, 756);
  const int mt = wgid / 12;
  const int rest = wgid - mt * 12;
  const int mat = rest >> 2;                           // 0=q 1=k 2=v
  const int nt = rest & 3;
  const int m0 = mt * 128, n0 = nt * 128;
  __shared__ __bf16 As[12288], Bs[12288];
  __shared__ int posTbl[128];                          // (b*16000+pos)<<7 | t  per tile row
  f32x4 acc[4][4] = {};
  const int wid = tid >> 6, lane = tid & 63;
  const int wm = (wid >> 1) << 6, wn = (wid & 1) << 6;
  const int lr = lane & 15, g = lane >> 4;

  if (tid < 128) {                                     // one divide per row
    int m = m0 + tid; if (m > 7999) m = 7999;
    const int b = m / 2000;
    const int s = m - b * 2000;
    const int t = s % 100;
    const int sp = s / 100;
    posTbl[tid] = ((b * 16000 + t * 20 + sp) << 7) | t;
  }
  // (visibility covered by the __syncthreads inside gemm_core_p2's prologue)

  gemm_core_p2(xb, wt + (size_t)mat * 262144, As, Bs, acc, m0, n0, tid, wm, wn, lr, g);

  const int hn = (n0 + wn) >> 6;                       // wave's 64 cols == one head
  const float* bias = (mat == 0) ? bq : (mat == 1) ? bk : bv;
  __bf16* outp = (mat == 0) ? qws : (mat == 1) ? kws : vws;
  const float qscale = (mat == 0) ? 0.125f : 1.0f;     // fold 1/sqrt(D) into q

#pragma unroll
  for (int i = 0; i < 4; ++i) {
#pragma unroll
    for (int r = 0; r < 4; ++r) {
      const int row = wm + i * 16 + g * 4 + r;
      const int m = m0 + row;
      if (m >= 8000) continue;
      const int pk = posTbl[row];
      const int t = pk & 127;
      const size_t ob = ((size_t)((pk >> 7) + hn * 2000)) * 64;
      if (mat == 2) {
        // V time-major contiguous rows (128B per row -> no write amplification)
#pragma unroll
        for (int j = 0; j < 4; ++j) {
          float v = acc[i][j][r] + bias[n0 + wn + j * 16 + lr];
          outp[ob + j * 16 + lr] = (__bf16)v;
        }
      } else {
        // RoPE in-register: d = j*16+lr (<32) pairs with d+32 in frag j+2
#pragma unroll
        for (int j = 0; j < 2; ++j) {
          const int dlo = j * 16 + lr;
          const float alo = acc[i][j][r]     + bias[n0 + wn + j * 16 + lr];
          const float ahi = acc[i][j + 2][r] + bias[n0 + wn + (j + 2) * 16 + lr];
          const float cs = ropeC[t * 32 + dlo], sn = ropeS[t * 32 + dlo];
          const float olo = (alo * cs - ahi * sn) * qscale;
          const float ohi = (ahi * cs + alo * sn) * qscale;
          outp[ob + dlo]      = (__bf16)olo;
          outp[ob + dlo + 32] = (__bf16)ohi;
        }
      }
    }
  }
}

// ---------------- P2: banded attention, MFMA, fused V-transpose-in-LDS ----------------
// One WAVE per (tq, h, b).  Single block barrier (Vs is the only
// block-cooperative LDS).  Vs staging is pos-fast: a 16-lane group writes one
// LDS row at 16 consecutive columns (conflict-free); global reads are
// 8B/lane at 128B stride, absorbed by L1/L2 (33KB window, 16x row reuse).
__global__ __launch_bounds__(256) void attn_kernel(
    const __bf16* __restrict__ qw, const __bf16* __restrict__ kw, const __bf16* __restrict__ vw,
    const int* __restrict__ amask, __bf16* __restrict__ aout)
{
  const int wid = threadIdx.x >> 6, lane = threadIdx.x & 63;
  const int tid = threadIdx.x;
  const int lr = lane & 15, g = lane >> 4;
  const int tq = blockIdx.x * 4 + wid;                 // 0..99
  const int h = blockIdx.y, b = blockIdx.z;

  int t0 = tq - 4; if (t0 < 0) t0 = 0;
  int t1 = tq + 4; if (t1 > 99) t1 = 99;
  const int k0 = t0 * 20;
  const int nk = (t1 - t0 + 1) * 20;                   // <= 180
  const int basew = k0 & ~7;                           // wave slot anchor (mult of 8)

  const int tq0 = blockIdx.x * 4;                      // block union window
  int t0b = tq0 - 4; if (t0b < 0) t0b = 0;
  int t1b = tq0 + 7; if (t1b > 99) t1b = 99;
  const int kb0 = (t0b * 20) & ~7;                     // block anchor (mult of 8)
  const int nks = (t1b + 1) * 20 - kb0;                // <= 264
  const int woff = basew - kb0;                        // mult of 8, <= 64

  __shared__ __bf16 Vs[64][264];                       // V^T block window, row 528B
  __shared__ __bf16 Pl[4][20][200];                    // per-wave P (b128 reads at floor)
  __shared__ float addm[4][192];                       // per-slot additive mask (0 or -1e9)

  const size_t hb = (size_t)(b * 8 + h) * 2000;
  const __bf16* qp = qw + (hb + (size_t)tq * 20) * 64;
  const __bf16* vp = vw + (hb + (size_t)kb0) * 64;

  // additive mask table over slots: window + attn_mask (per-wave)
  for (int k = lane; k < 192; k += 64) {
    const int kg = basew + k;
    float v = -1e9f;
    if (kg >= k0 && kg < k0 + nk) {
      const int tk = kg / 20;
      const int spk = kg - tk * 20;
      if (amask[b * 2000 + spk * 100 + tk] != 0) v = 0.0f;
    }
    addm[wid][k] = v;
  }

  // stage V window transposed, pos-fast: Vs[d][slot] <- v[kb0+slot][d].
  // Consecutive lanes share dq and write consecutive columns of each row
  // (32B contiguous per 16-lane group -> no bank conflicts).  Zero-fill pad.
  for (int idx = tid; idx < 264 * 16; idx += 256) {
    const int dq = idx / 264;                          // 0..15 (slow)
    const int pr = idx - dq * 264;                     // 0..263 (fast)
    const int d4 = dq * 4;
    union { ushort4 u; __bf16 e[4]; } p;
    p.u = make_ushort4(0, 0, 0, 0);
    if (pr < nks) p.u = *(const ushort4*)(vp + (size_t)pr * 64 + d4);
    Vs[d4 + 0][pr] = p.e[0];
    Vs[d4 + 1][pr] = p.e[1];
    Vs[d4 + 2][pr] = p.e[2];
    Vs[d4 + 3][pr] = p.e[3];
  }

  // Q^T B-frags: col=q (lane&15), d-contiguous from global
  bf16x8 qf[2][2];
#pragma unroll
  for (int jq = 0; jq < 2; ++jq) {
    int q = jq * 16 + lr; if (q > 19) q = 19;
#pragma unroll
    for (int ks = 0; ks < 2; ++ks)
      qf[jq][ks] = *(const bf16x8*)(qp + q * 64 + ks * 32 + g * 8);
  }

  // QK^T: acc[i][jq] = S^T tile rows [i*16,i*16+16) x q cols
  f32x4 acc[12][2] = {};
  __builtin_amdgcn_s_setprio(1);
#pragma unroll
  for (int i = 0; i < 12; ++i) {
    int krow = basew + i * 16 + lr; if (krow > 1999) krow = 1999;  // dup rows masked by addm
    const __bf16* kr = kw + (hb + (size_t)krow) * 64;
    const bf16x8 af0 = *(const bf16x8*)(kr + g * 8);
    const bf16x8 af1 = *(const bf16x8*)(kr + 32 + g * 8);
    acc[i][0] = __builtin_amdgcn_mfma_f32_16x16x32_bf16(af0, qf[0][0], acc[i][0], 0, 0, 0);
    acc[i][0] = __builtin_amdgcn_mfma_f32_16x16x32_bf16(af1, qf[0][1], acc[i][0], 0, 0, 0);
    acc[i][1] = __builtin_amdgcn_mfma_f32_16x16x32_bf16(af0, qf[1][0], acc[i][1], 0, 0, 0);
    acc[i][1] = __builtin_amdgcn_mfma_f32_16x16x32_bf16(af1, qf[1][1], acc[i][1], 0, 0, 0);
  }
  __builtin_amdgcn_s_setprio(0);

  // mask + softmax per q-col (reads addm[wid] — own wave's LDS writes)
#pragma unroll
  for (int jq = 0; jq < 2; ++jq) {
    float mx = -1e30f;
#pragma unroll
    for (int i = 0; i < 12; ++i)
#pragma unroll
      for (int r = 0; r < 4; ++r) {
        acc[i][jq][r] += addm[wid][i * 16 + g * 4 + r];
        mx = fmaxf(mx, acc[i][jq][r]);
      }
    mx = fmaxf(mx, __shfl_xor(mx, 16));
    mx = fmaxf(mx, __shfl_xor(mx, 32));
    float sm = 0.0f;
#pragma unroll
    for (int i = 0; i < 12; ++i)
#pragma unroll
      for (int r = 0; r < 4; ++r) {
        const float p = __expf(acc[i][jq][r] - mx);
        acc[i][jq][r] = p;
        sm += p;
      }
    sm += __shfl_xor(sm, 16);
    sm += __shfl_xor(sm, 32);
    const float rinv = 1.0f / sm;
    const int q = jq * 16 + lr;
    if (q < 20) {
#pragma unroll
      for (int i = 0; i < 12; ++i) {
        union { ushort4 u; __bf16 e[4]; } pk;
        pk.e[0] = (__bf16)(acc[i][jq][0] * rinv);
        pk.e[1] = (__bf16)(acc[i][jq][1] * rinv);
        pk.e[2] = (__bf16)(acc[i][jq][2] * rinv);
        pk.e[3] = (__bf16)(acc[i][jq][3] * rinv);
        *(ushort4*)&Pl[wid][q][i * 16 + g * 4] = pk.u;
      }
    }
  }

  __syncthreads();   // Vs (block-cooperative) visible; Pl is per-wave

  // PV: out[q][d] = P[q][slot] * Vs[d][woff+slot]; A=P, B=Vs, both LDS
  f32x4 acc2[2][4] = {};
  __builtin_amdgcn_s_setprio(1);
#pragma unroll
  for (int kb = 0; kb < 6; ++kb) {
    const int kvloc = woff + kb * 32 + g * 8;          // <= 255, 8-aligned
    bf16x8 bfv[4];
#pragma unroll
    for (int j2 = 0; j2 < 4; ++j2)
      bfv[j2] = *(const bf16x8*)&Vs[j2 * 16 + lr][kvloc];
#pragma unroll
    for (int i2 = 0; i2 < 2; ++i2) {
      int qr = i2 * 16 + lr; if (qr > 19) qr = 19;
      const bf16x8 pa = *(const bf16x8*)&Pl[wid][qr][kb * 32 + g * 8];
#pragma unroll
      for (int j2 = 0; j2 < 4; ++j2)
        acc2[i2][j2] = __builtin_amdgcn_mfma_f32_16x16x32_bf16(pa, bfv[j2], acc2[i2][j2], 0, 0, 0);
    }
  }
  __builtin_amdgcn_s_setprio(0);

  // store: row q = i2*16 + g*4 + r, col d = j2*16 + lr; back to space-major
#pragma unroll
  for (int i2 = 0; i2 < 2; ++i2)
#pragma unroll
    for (int r = 0; r < 4; ++r) {
      const int q = i2 * 16 + g * 4 + r;
      if (q < 20) {
        const size_t ob = ((size_t)b * 2000 + q * 100 + tq) * 512 + h * 64;
#pragma unroll
        for (int j2 = 0; j2 < 4; ++j2)
          aout[ob + j2 * 16 + lr] = (__bf16)acc2[i2][j2][r];
      }
    }
}

// ---------------- P3: output GEMM — 64Mx128N, depth-2 counted, 500 blocks ----------------
__global__ __launch_bounds__(256) void out_gemm(
    const __bf16* __restrict__ ab, const __bf16* __restrict__ wot,
    const float* __restrict__ bo, float* __restrict__ out)
{
  const int tid = threadIdx.x;
  const int wgid = xcd_swz(blockIdx.x, 500);
  const int mt = wgid >> 2, nt = wgid & 3;
  const int m0 = mt * 64, n0 = nt * 128;               // 125*64 = 8000 exact
  __shared__ __bf16 As[3 * 2048];
  __shared__ __bf16 Bs[3 * 4096];
  f32x4 acc[2][4] = {};
  const int wid = tid >> 6, lane = tid & 63;
  const int wm = (wid >> 1) << 5, wn = (wid & 1) << 6; // wave tile 32M x 64N
  const int lr = lane & 15, g = lane >> 4;

  const __bf16* a_src = ab + (size_t)(m0 + (tid >> 2)) * 512 + (tid & 3) * 8;

#define STGO(BUF, KK) do {                                                       \
    gload16(a_src + (KK), As + (BUF) * 2048 + tid * 8);                          \
    _Pragma("unroll")                                                            \
    for (int jj = 0; jj < 2; ++jj) {                                             \
      const int c = tid + jj * 256;                                              \
      gload16(wot + (size_t)(n0 + (c >> 2)) * 512 + (KK) + (c & 3) * 8,          \
              Bs + (BUF) * 4096 + c * 8);                                        \
    }                                                                            \
  } while (0)

  STGO(0, 0);
  STGO(1, 32);
  __syncthreads();

  int cur = 0, st = 2;
  for (int k = 0; k < 14; ++k) {
    STGO(st, (k + 2) * 32);
    {
      bf16x8 af[2], bfr[4];
#pragma unroll
      for (int f = 0; f < 2; ++f)
        af[f] = *(const bf16x8*)(As + cur * 2048 + (wm + f * 16 + lr) * 32 + g * 8);
#pragma unroll
      for (int f = 0; f < 4; ++f)
        bfr[f] = *(const bf16x8*)(Bs + cur * 4096 + (wn + f * 16 + lr) * 32 + g * 8);
#pragma unroll
      for (int i = 0; i < 2; ++i)
#pragma unroll
        for (int j = 0; j < 4; ++j)
          acc[i][j] = __builtin_amdgcn_mfma_f32_16x16x32_bf16(af[i], bfr[j], acc[i][j], 0, 0, 0);
    }
    asm volatile("s_waitcnt vmcnt(3)" ::: "memory");   // stage(k+1) done; stage(k+2) in flight
    __builtin_amdgcn_s_barrier();
    __builtin_amdgcn_sched_barrier(0);
    if (++cur == 3) cur = 0;
    if (++st == 3) st = 0;
  }
#pragma unroll
  for (int tail = 0; tail < 2; ++tail) {
    const int buf = (tail == 0) ? 2 : 0;               // k=14 -> buf2, k=15 -> buf0
    if (tail == 0) {
      asm volatile("s_waitcnt vmcnt(0)" ::: "memory"); // drain stage(15) before its use next
    }
    bf16x8 af[2], bfr[4];
#pragma unroll
    for (int f = 0; f < 2; ++f)
      af[f] = *(const bf16x8*)(As + buf * 2048 + (wm + f * 16 + lr) * 32 + g * 8);
#pragma unroll
    for (int f = 0; f < 4; ++f)
      bfr[f] = *(const bf16x8*)(Bs + buf * 4096 + (wn + f * 16 + lr) * 32 + g * 8);
#pragma unroll
    for (int i = 0; i < 2; ++i)
#pragma unroll
      for (int j = 0; j < 4; ++j)
        acc[i][j] = __builtin_amdgcn_mfma_f32_16x16x32_bf16(af[i], bfr[j], acc[i][j], 0, 0, 0);
  }
#undef STGO

#pragma unroll
  for (int i = 0; i < 2; ++i) {
#pragma unroll
    for (int r = 0; r < 4; ++r) {
      const int m = m0 + wm + i * 16 + g * 4 + r;      // always < 8000
#pragma unroll
      for (int j = 0; j < 4; ++j) {
        const int n = n0 + wn + j * 16 + lr;
        out[(size_t)m * 512 + n] = acc[i][j][r] + bo[n];
      }
    }
  }
}

extern "C" void kernel_launch(void* const* d_in, const int* in_sizes, int n_in,
                              void* d_out, int out_size, void* d_ws, size_t ws_size,
                              hipStream_t stream) {
  const float* x   = (const float*)d_in[0];
  const int* amask = (const int*)d_in[1];
  const float* Wq = (const float*)d_in[3];
  const float* bq = (const float*)d_in[4];
  const float* Wk = (const float*)d_in[5];
  const float* bk = (const float*)d_in[6];
  const float* Wv = (const float*)d_in[7];
  const float* bv = (const float*)d_in[8];
  const float* Wo = (const float*)d_in[9];
  const float* bo = (const float*)d_in[10];
  float* out = (float*)d_out;

  char* ws = (char*)d_ws;
  __bf16* xb    = (__bf16*)(ws + O_XB);
  __bf16* wt    = (__bf16*)(ws + O_WT);
  __bf16* qws   = (__bf16*)(ws + O_Q);
  __bf16* kws   = (__bf16*)(ws + O_K);
  __bf16* vws   = (__bf16*)(ws + O_V);
  float*  ropeC = (float*)(ws + O_RC);
  float*  ropeS = (float*)(ws + O_RS);
  __bf16* aout  = (__bf16*)(ws + O_XB);   // reuse xb region after qkv consumed it

  prep_kernel<<<4256, 256, 0, stream>>>(x, Wq, Wk, Wv, Wo, xb, wt, ropeC, ropeS);
  qkv_gemm<<<756, 256, 0, stream>>>(xb, wt, bq, bk, bv, ropeC, ropeS, qws, kws, vws);
  attn_kernel<<<dim3(25, 8, 4), 256, 0, stream>>>(qws, kws, vws, amask, aout);
  out_gemm<<<500, 256, 0, stream>>>(aout, wt + 3 * 262144, bo, out);
}

// Round 11
// 82.272 us; speedup vs baseline: 1.0391x; 1.0391x over previous
//
#include <hip/hip_runtime.h>
#include <hip/hip_bf16.h>
#include <stdint.h>

// B=4, T=100, SP=20, S=2000, H=512, NH=8, D=64, CF=CB=4
// Token order space-major: s = sp*100 + t.  Internally q/k/v are permuted to
// time-major (pos = t*20 + sp) so the banded mask (|dt|<=4) becomes a
// contiguous key window of <=180 keys.  V stays time-major in global; the
// attention kernel stages its block's union V-window into LDS TRANSPOSED.
// Vs row stride 266 elem (133 dwords === 5 mod 32) -> the d-fast transpose
// writes (rows 4k, same col) spread over 8 banks = 2-way = free, while the
// global side stays fully coalesced (16 lanes cover one 128B V row).
// GEMMs: BK=32, global_load_lds staging, 3-buffer depth-2 pipeline with
// COUNTED s_waitcnt (never 0 in the loop), XCD-chunked block swizzle.
// qkv: 128Mx128N @ 756 blocks (~3/CU); out: 64Mx128N @ 500 blocks (~2/CU).

typedef __bf16 bf16x8 __attribute__((ext_vector_type(8)));
typedef float f32x4 __attribute__((ext_vector_type(4)));

// ---- workspace layout (bytes, all 16B aligned) ----
static const size_t O_XB = 0;                  // bf16 x [8000][512]; reused as attn-out after qkv
static const size_t O_WT = 8192000;            // bf16 W^T x4, each [512 n][512 k]
static const size_t O_Q  = 10289152;           // bf16 q, time-major [4][8][2000][64] (pre-scaled by 1/8)
static const size_t O_K  = 18481152;           // bf16 k, time-major
static const size_t O_V  = 26673152;           // bf16 v, time-major [4][8][2000][64]
static const size_t O_RC = 34865152;           // f32 rope cos [100][32]
static const size_t O_RS = 34877952;           // f32 rope sin [100][32]

__device__ inline void gload16(const void* g, void* l) {
  __builtin_amdgcn_global_load_lds((const __attribute__((address_space(1))) void*)g,
                                   (__attribute__((address_space(3))) void*)l, 16, 0, 0);
}

// bijective XCD-chunk swizzle (m204)
__device__ inline int xcd_swz(int orig, int nwg) {
  const int q8 = nwg >> 3, r8 = nwg & 7;
  const int xcd = orig & 7;
  return (xcd < r8 ? xcd * (q8 + 1) : r8 * (q8 + 1) + (xcd - r8) * q8) + (orig >> 3);
}

// ---------------- P0: prep — x f32->bf16, LDS-tiled W transpose, rope ----------------
__global__ __launch_bounds__(256) void prep_kernel(
    const float* __restrict__ x, const float* __restrict__ Wq, const float* __restrict__ Wk,
    const float* __restrict__ Wv, const float* __restrict__ Wo,
    __bf16* __restrict__ xb, __bf16* __restrict__ wt,
    float* __restrict__ ropeC, float* __restrict__ ropeS)
{
  __shared__ float tile[64][65];
  const int tid = threadIdx.x;
  const int bx = blockIdx.x;
  if (bx < 4000) {                                     // x cvt: 1,024,000 float4s
    const int idx = bx * 256 + tid;
    float4 v = ((const float4*)x)[idx];
    union { ushort4 u; __bf16 b[4]; } p;
    p.b[0] = (__bf16)v.x; p.b[1] = (__bf16)v.y; p.b[2] = (__bf16)v.z; p.b[3] = (__bf16)v.w;
    ((ushort4*)xb)[idx] = p.u;
    return;
  }
  const int wb = bx - 4000;                            // 0..255: W transpose tiles
  const int mat = wb >> 6, sub = wb & 63;
  const int tk = (sub >> 3) * 64, tn = (sub & 7) * 64;
  const float* W = (mat == 0) ? Wq : (mat == 1) ? Wk : (mat == 2) ? Wv : Wo;
#pragma unroll
  for (int it = 0; it < 16; ++it) {                    // coalesced read: lanes span n
    const int idx = it * 256 + tid;
    const int kl = idx >> 6, nl = idx & 63;
    tile[kl][nl] = W[(size_t)(tk + kl) * 512 + tn + nl];
  }
  __syncthreads();
#pragma unroll
  for (int it = 0; it < 16; ++it) {                    // coalesced write: lanes span k
    const int idx = it * 256 + tid;
    const int nl = idx >> 6, kl = idx & 63;
    wt[(size_t)mat * 262144 + (size_t)(tn + nl) * 512 + tk + kl] = (__bf16)tile[kl][nl];
  }
  if (wb == 0) {                                       // rope tables [t][i]
    for (int idx = tid; idx < 3200; idx += 256) {
      const int t = idx >> 5, i = idx & 31;
      const float f = (float)t * powf(10000.0f, -(float)i / 32.0f);
      ropeC[idx] = cosf(f);
      ropeS[idx] = sinf(f);
    }
  }
}

// ---------------- GEMM: one 16-MFMA step from LDS buffers (128M tile) ----------------
__device__ inline void mfma_step(const __bf16* ab, const __bf16* bb,
                                 f32x4 (&acc)[4][4], int wm, int wn, int lr, int g)
{
  bf16x8 af[4], bfr[4];
#pragma unroll
  for (int f = 0; f < 4; ++f) {
    af[f]  = *(const bf16x8*)(ab + (wm + f * 16 + lr) * 32 + g * 8);
    bfr[f] = *(const bf16x8*)(bb + (wn + f * 16 + lr) * 32 + g * 8);
  }
#pragma unroll
  for (int i = 0; i < 4; ++i)
#pragma unroll
    for (int j = 0; j < 4; ++j)
      acc[i][j] = __builtin_amdgcn_mfma_f32_16x16x32_bf16(af[i], bfr[j], acc[i][j], 0, 0, 0);
}

// ---------------- GEMM core: C[128x128] = A[128x512]*B^T, BK=32, depth-2 counted ----------------
// As/Bs: 3 buffers x 4096 bf16.  Loads for K-step k+2 issued at iter k, waited
// (vmcnt(4)) at the END of iter k -> stage(k+1) complete, stage(k+2) in flight.
__device__ inline void gemm_core_p2(const __bf16* __restrict__ A, const __bf16* __restrict__ Bm,
                                    __bf16* As, __bf16* Bs, f32x4 (&acc)[4][4],
                                    int m0, int n0, int tid, int wm, int wn, int lr, int g)
{
  const int r0 = tid >> 2;          // staging row within half-tile (0..63)
  const int aq = tid & 3;           // 16B quad within 64B row
  int gm0 = m0 + r0;      if (gm0 > 7999) gm0 = 7999;   // clamp M edge (dup rows, stores guarded)
  int gm1 = m0 + r0 + 64; if (gm1 > 7999) gm1 = 7999;
  const __bf16* a0 = A + (size_t)gm0 * 512 + aq * 8;
  const __bf16* a1 = A + (size_t)gm1 * 512 + aq * 8;
  const __bf16* b0 = Bm + (size_t)(n0 + r0) * 512 + aq * 8;
  const __bf16* b1 = Bm + (size_t)(n0 + r0 + 64) * 512 + aq * 8;

#define STAGE_QK(J, BUF) do {                                      \
    gload16(a0 + (J) * 32, As + (BUF) * 4096 + tid * 8);           \
    gload16(a1 + (J) * 32, As + (BUF) * 4096 + tid * 8 + 2048);    \
    gload16(b0 + (J) * 32, Bs + (BUF) * 4096 + tid * 8);           \
    gload16(b1 + (J) * 32, Bs + (BUF) * 4096 + tid * 8 + 2048);    \
  } while (0)

  STAGE_QK(0, 0);
  STAGE_QK(1, 1);
  __syncthreads();                  // full drain once (also publishes posTbl)

  int cur = 0, st = 2;
  for (int k = 0; k < 14; ++k) {
    STAGE_QK(k + 2, st);
    mfma_step(As + cur * 4096, Bs + cur * 4096, acc, wm, wn, lr, g);
    asm volatile("s_waitcnt vmcnt(4)" ::: "memory");   // stage(k+1) done; stage(k+2) in flight
    __builtin_amdgcn_s_barrier();
    __builtin_amdgcn_sched_barrier(0);
    if (++cur == 3) cur = 0;
    if (++st == 3) st = 0;
  }
  // k = 14: cur == 2
  mfma_step(As + 2 * 4096, Bs + 2 * 4096, acc, wm, wn, lr, g);
  asm volatile("s_waitcnt vmcnt(0)" ::: "memory");     // drain stage(15)
  __builtin_amdgcn_s_barrier();
  __builtin_amdgcn_sched_barrier(0);
  // k = 15: buffer 0
  mfma_step(As, Bs, acc, wm, wn, lr, g);
#undef STAGE_QK
}

// ---------------- P1: QKV GEMM + bias + RoPE + time-major permute ----------------
// 1D grid 756, XCD-swizzled; wgid -> (mt, mat, nt) with A-panel sharers contiguous.
__global__ __launch_bounds__(256) void qkv_gemm(
    const __bf16* __restrict__ xb, const __bf16* __restrict__ wt,
    const float* __restrict__ bq, const float* __restrict__ bk, const float* __restrict__ bv,
    const float* __restrict__ ropeC, const float* __restrict__ ropeS,
    __bf16* __restrict__ qws, __bf16* __restrict__ kws, __bf16* __restrict__ vws)
{
  const int tid = threadIdx.x;
  const int wgid = xcd_swz(blockIdx.x, 756);
  const int mt = wgid / 12;
  const int rest = wgid - mt * 12;
  const int mat = rest >> 2;                           // 0=q 1=k 2=v
  const int nt = rest & 3;
  const int m0 = mt * 128, n0 = nt * 128;
  __shared__ __bf16 As[12288], Bs[12288];
  __shared__ int posTbl[128];                          // (b*16000+pos)<<7 | t  per tile row
  f32x4 acc[4][4] = {};
  const int wid = tid >> 6, lane = tid & 63;
  const int wm = (wid >> 1) << 6, wn = (wid & 1) << 6;
  const int lr = lane & 15, g = lane >> 4;

  if (tid < 128) {                                     // one divide per row
    int m = m0 + tid; if (m > 7999) m = 7999;
    const int b = m / 2000;
    const int s = m - b * 2000;
    const int t = s % 100;
    const int sp = s / 100;
    posTbl[tid] = ((b * 16000 + t * 20 + sp) << 7) | t;
  }
  // (visibility covered by the __syncthreads inside gemm_core_p2's prologue)

  gemm_core_p2(xb, wt + (size_t)mat * 262144, As, Bs, acc, m0, n0, tid, wm, wn, lr, g);

  const int hn = (n0 + wn) >> 6;                       // wave's 64 cols == one head
  const float* bias = (mat == 0) ? bq : (mat == 1) ? bk : bv;
  __bf16* outp = (mat == 0) ? qws : (mat == 1) ? kws : vws;
  const float qscale = (mat == 0) ? 0.125f : 1.0f;     // fold 1/sqrt(D) into q

#pragma unroll
  for (int i = 0; i < 4; ++i) {
#pragma unroll
    for (int r = 0; r < 4; ++r) {
      const int row = wm + i * 16 + g * 4 + r;
      const int m = m0 + row;
      if (m >= 8000) continue;
      const int pk = posTbl[row];
      const int t = pk & 127;
      const size_t ob = ((size_t)((pk >> 7) + hn * 2000)) * 64;
      if (mat == 2) {
        // V time-major contiguous rows (128B per row -> no write amplification)
#pragma unroll
        for (int j = 0; j < 4; ++j) {
          float v = acc[i][j][r] + bias[n0 + wn + j * 16 + lr];
          outp[ob + j * 16 + lr] = (__bf16)v;
        }
      } else {
        // RoPE in-register: d = j*16+lr (<32) pairs with d+32 in frag j+2
#pragma unroll
        for (int j = 0; j < 2; ++j) {
          const int dlo = j * 16 + lr;
          const float alo = acc[i][j][r]     + bias[n0 + wn + j * 16 + lr];
          const float ahi = acc[i][j + 2][r] + bias[n0 + wn + (j + 2) * 16 + lr];
          const float cs = ropeC[t * 32 + dlo], sn = ropeS[t * 32 + dlo];
          const float olo = (alo * cs - ahi * sn) * qscale;
          const float ohi = (ahi * cs + alo * sn) * qscale;
          outp[ob + dlo]      = (__bf16)olo;
          outp[ob + dlo + 32] = (__bf16)ohi;
        }
      }
    }
  }
}

// ---------------- P2: banded attention, MFMA, fused V-transpose-in-LDS ----------------
// One WAVE per (tq, h, b).  Single block barrier (Vs is the only
// block-cooperative LDS).  Vs staging is d-fast (16 lanes cover one 128B V
// row -> coalesced global); Vs row stride 266 (133 dwords === 5 mod 32) makes
// the stride-4-row write groups 2-way on banks = free.
__global__ __launch_bounds__(256) void attn_kernel(
    const __bf16* __restrict__ qw, const __bf16* __restrict__ kw, const __bf16* __restrict__ vw,
    const int* __restrict__ amask, __bf16* __restrict__ aout)
{
  const int wid = threadIdx.x >> 6, lane = threadIdx.x & 63;
  const int tid = threadIdx.x;
  const int lr = lane & 15, g = lane >> 4;
  const int tq = blockIdx.x * 4 + wid;                 // 0..99
  const int h = blockIdx.y, b = blockIdx.z;

  int t0 = tq - 4; if (t0 < 0) t0 = 0;
  int t1 = tq + 4; if (t1 > 99) t1 = 99;
  const int k0 = t0 * 20;
  const int nk = (t1 - t0 + 1) * 20;                   // <= 180
  const int basew = k0 & ~7;                           // wave slot anchor (mult of 8)

  const int tq0 = blockIdx.x * 4;                      // block union window
  int t0b = tq0 - 4; if (t0b < 0) t0b = 0;
  int t1b = tq0 + 7; if (t1b > 99) t1b = 99;
  const int kb0 = (t0b * 20) & ~7;                     // block anchor (mult of 8)
  const int nks = (t1b + 1) * 20 - kb0;                // <= 264
  const int woff = basew - kb0;                        // mult of 8, <= 64

  __shared__ __bf16 Vs[64][266];                       // V^T block window, row 532B (5 mod 32 dwords)
  __shared__ __bf16 Pl[4][20][200];                    // per-wave P (b128 reads at floor)
  __shared__ float addm[4][192];                       // per-slot additive mask (0 or -1e9)

  const size_t hb = (size_t)(b * 8 + h) * 2000;
  const __bf16* qp = qw + (hb + (size_t)tq * 20) * 64;
  const __bf16* vp = vw + (hb + (size_t)kb0) * 64;

  // additive mask table over slots: window + attn_mask (per-wave)
  for (int k = lane; k < 192; k += 64) {
    const int kg = basew + k;
    float v = -1e9f;
    if (kg >= k0 && kg < k0 + nk) {
      const int tk = kg / 20;
      const int spk = kg - tk * 20;
      if (amask[b * 2000 + spk * 100 + tk] != 0) v = 0.0f;
    }
    addm[wid][k] = v;
  }

  // stage V window transposed, d-fast: Vs[d][slot] <- v[kb0+slot][d].
  // 16 consecutive lanes read one 128B global row (coalesced); writes land on
  // rows {0,4,...,60} same col -> 8 banks x 2-way with the 266 stride (free).
  for (int idx = tid; idx < 264 * 16; idx += 256) {
    const int pr = idx >> 4, d4 = (idx & 15) * 4;
    union { ushort4 u; __bf16 e[4]; } p;
    p.u = make_ushort4(0, 0, 0, 0);
    if (pr < nks) p.u = *(const ushort4*)(vp + (size_t)pr * 64 + d4);
    Vs[d4 + 0][pr] = p.e[0];
    Vs[d4 + 1][pr] = p.e[1];
    Vs[d4 + 2][pr] = p.e[2];
    Vs[d4 + 3][pr] = p.e[3];
  }

  // Q^T B-frags: col=q (lane&15), d-contiguous from global
  bf16x8 qf[2][2];
#pragma unroll
  for (int jq = 0; jq < 2; ++jq) {
    int q = jq * 16 + lr; if (q > 19) q = 19;
#pragma unroll
    for (int ks = 0; ks < 2; ++ks)
      qf[jq][ks] = *(const bf16x8*)(qp + q * 64 + ks * 32 + g * 8);
  }

  // QK^T: acc[i][jq] = S^T tile rows [i*16,i*16+16) x q cols
  f32x4 acc[12][2] = {};
  __builtin_amdgcn_s_setprio(1);
#pragma unroll
  for (int i = 0; i < 12; ++i) {
    int krow = basew + i * 16 + lr; if (krow > 1999) krow = 1999;  // dup rows masked by addm
    const __bf16* kr = kw + (hb + (size_t)krow) * 64;
    const bf16x8 af0 = *(const bf16x8*)(kr + g * 8);
    const bf16x8 af1 = *(const bf16x8*)(kr + 32 + g * 8);
    acc[i][0] = __builtin_amdgcn_mfma_f32_16x16x32_bf16(af0, qf[0][0], acc[i][0], 0, 0, 0);
    acc[i][0] = __builtin_amdgcn_mfma_f32_16x16x32_bf16(af1, qf[0][1], acc[i][0], 0, 0, 0);
    acc[i][1] = __builtin_amdgcn_mfma_f32_16x16x32_bf16(af0, qf[1][0], acc[i][1], 0, 0, 0);
    acc[i][1] = __builtin_amdgcn_mfma_f32_16x16x32_bf16(af1, qf[1][1], acc[i][1], 0, 0, 0);
  }
  __builtin_amdgcn_s_setprio(0);

  // mask + softmax per q-col (reads addm[wid] — own wave's LDS writes)
#pragma unroll
  for (int jq = 0; jq < 2; ++jq) {
    float mx = -1e30f;
#pragma unroll
    for (int i = 0; i < 12; ++i)
#pragma unroll
      for (int r = 0; r < 4; ++r) {
        acc[i][jq][r] += addm[wid][i * 16 + g * 4 + r];
        mx = fmaxf(mx, acc[i][jq][r]);
      }
    mx = fmaxf(mx, __shfl_xor(mx, 16));
    mx = fmaxf(mx, __shfl_xor(mx, 32));
    float sm = 0.0f;
#pragma unroll
    for (int i = 0; i < 12; ++i)
#pragma unroll
      for (int r = 0; r < 4; ++r) {
        const float p = __expf(acc[i][jq][r] - mx);
        acc[i][jq][r] = p;
        sm += p;
      }
    sm += __shfl_xor(sm, 16);
    sm += __shfl_xor(sm, 32);
    const float rinv = 1.0f / sm;
    const int q = jq * 16 + lr;
    if (q < 20) {
#pragma unroll
      for (int i = 0; i < 12; ++i) {
        union { ushort4 u; __bf16 e[4]; } pk;
        pk.e[0] = (__bf16)(acc[i][jq][0] * rinv);
        pk.e[1] = (__bf16)(acc[i][jq][1] * rinv);
        pk.e[2] = (__bf16)(acc[i][jq][2] * rinv);
        pk.e[3] = (__bf16)(acc[i][jq][3] * rinv);
        *(ushort4*)&Pl[wid][q][i * 16 + g * 4] = pk.u;
      }
    }
  }

  __syncthreads();   // Vs (block-cooperative) visible; Pl is per-wave

  // PV: out[q][d] = P[q][slot] * Vs[d][woff+slot]; A=P, B=Vs, both LDS
  f32x4 acc2[2][4] = {};
  __builtin_amdgcn_s_setprio(1);
#pragma unroll
  for (int kb = 0; kb < 6; ++kb) {
    const int kvloc = woff + kb * 32 + g * 8;          // <= 255, 8-aligned
    bf16x8 bfv[4];
#pragma unroll
    for (int j2 = 0; j2 < 4; ++j2)
      bfv[j2] = *(const bf16x8*)&Vs[j2 * 16 + lr][kvloc];
#pragma unroll
    for (int i2 = 0; i2 < 2; ++i2) {
      int qr = i2 * 16 + lr; if (qr > 19) qr = 19;
      const bf16x8 pa = *(const bf16x8*)&Pl[wid][qr][kb * 32 + g * 8];
#pragma unroll
      for (int j2 = 0; j2 < 4; ++j2)
        acc2[i2][j2] = __builtin_amdgcn_mfma_f32_16x16x32_bf16(pa, bfv[j2], acc2[i2][j2], 0, 0, 0);
    }
  }
  __builtin_amdgcn_s_setprio(0);

  // store: row q = i2*16 + g*4 + r, col d = j2*16 + lr; back to space-major
#pragma unroll
  for (int i2 = 0; i2 < 2; ++i2)
#pragma unroll
    for (int r = 0; r < 4; ++r) {
      const int q = i2 * 16 + g * 4 + r;
      if (q < 20) {
        const size_t ob = ((size_t)b * 2000 + q * 100 + tq) * 512 + h * 64;
#pragma unroll
        for (int j2 = 0; j2 < 4; ++j2)
          aout[ob + j2 * 16 + lr] = (__bf16)acc2[i2][j2][r];
      }
    }
}

// ---------------- P3: output GEMM — 64Mx128N, depth-2 counted, 500 blocks ----------------
__global__ __launch_bounds__(256) void out_gemm(
    const __bf16* __restrict__ ab, const __bf16* __restrict__ wot,
    const float* __restrict__ bo, float* __restrict__ out)
{
  const int tid = threadIdx.x;
  const int wgid = xcd_swz(blockIdx.x, 500);
  const int mt = wgid >> 2, nt = wgid & 3;
  const int m0 = mt * 64, n0 = nt * 128;               // 125*64 = 8000 exact
  __shared__ __bf16 As[3 * 2048];
  __shared__ __bf16 Bs[3 * 4096];
  f32x4 acc[2][4] = {};
  const int wid = tid >> 6, lane = tid & 63;
  const int wm = (wid >> 1) << 5, wn = (wid & 1) << 6; // wave tile 32M x 64N
  const int lr = lane & 15, g = lane >> 4;

  const __bf16* a_src = ab + (size_t)(m0 + (tid >> 2)) * 512 + (tid & 3) * 8;

#define STGO(BUF, KK) do {                                                       \
    gload16(a_src + (KK), As + (BUF) * 2048 + tid * 8);                          \
    _Pragma("unroll")                                                            \
    for (int jj = 0; jj < 2; ++jj) {                                             \
      const int c = tid + jj * 256;                                              \
      gload16(wot + (size_t)(n0 + (c >> 2)) * 512 + (KK) + (c & 3) * 8,          \
              Bs + (BUF) * 4096 + c * 8);                                        \
    }                                                                            \
  } while (0)

  STGO(0, 0);
  STGO(1, 32);
  __syncthreads();

  int cur = 0, st = 2;
  for (int k = 0; k < 14; ++k) {
    STGO(st, (k + 2) * 32);
    {
      bf16x8 af[2], bfr[4];
#pragma unroll
      for (int f = 0; f < 2; ++f)
        af[f] = *(const bf16x8*)(As + cur * 2048 + (wm + f * 16 + lr) * 32 + g * 8);
#pragma unroll
      for (int f = 0; f < 4; ++f)
        bfr[f] = *(const bf16x8*)(Bs + cur * 4096 + (wn + f * 16 + lr) * 32 + g * 8);
#pragma unroll
      for (int i = 0; i < 2; ++i)
#pragma unroll
        for (int j = 0; j < 4; ++j)
          acc[i][j] = __builtin_amdgcn_mfma_f32_16x16x32_bf16(af[i], bfr[j], acc[i][j], 0, 0, 0);
    }
    asm volatile("s_waitcnt vmcnt(3)" ::: "memory");   // stage(k+1) done; stage(k+2) in flight
    __builtin_amdgcn_s_barrier();
    __builtin_amdgcn_sched_barrier(0);
    if (++cur == 3) cur = 0;
    if (++st == 3) st = 0;
  }
#pragma unroll
  for (int tail = 0; tail < 2; ++tail) {
    const int buf = (tail == 0) ? 2 : 0;               // k=14 -> buf2, k=15 -> buf0
    if (tail == 0) {
      asm volatile("s_waitcnt vmcnt(0)" ::: "memory"); // drain stage(15) before its use next
    }
    bf16x8 af[2], bfr[4];
#pragma unroll
    for (int f = 0; f < 2; ++f)
      af[f] = *(const bf16x8*)(As + buf * 2048 + (wm + f * 16 + lr) * 32 + g * 8);
#pragma unroll
    for (int f = 0; f < 4; ++f)
      bfr[f] = *(const bf16x8*)(Bs + buf * 4096 + (wn + f * 16 + lr) * 32 + g * 8);
#pragma unroll
    for (int i = 0; i < 2; ++i)
#pragma unroll
      for (int j = 0; j < 4; ++j)
        acc[i][j] = __builtin_amdgcn_mfma_f32_16x16x32_bf16(af[i], bfr[j], acc[i][j], 0, 0, 0);
  }
#undef STGO

#pragma unroll
  for (int i = 0; i < 2; ++i) {
#pragma unroll
    for (int r = 0; r < 4; ++r) {
      const int m = m0 + wm + i * 16 + g * 4 + r;      // always < 8000
#pragma unroll
      for (int j = 0; j < 4; ++j) {
        const int n = n0 + wn + j * 16 + lr;
        out[(size_t)m * 512 + n] = acc[i][j][r] + bo[n];
      }
    }
  }
}

extern "C" void kernel_launch(void* const* d_in, const int* in_sizes, int n_in,
                              void* d_out, int out_size, void* d_ws, size_t ws_size,
                              hipStream_t stream) {
  const float* x   = (const float*)d_in[0];
  const int* amask = (const int*)d_in[1];
  const float* Wq = (const float*)d_in[3];
  const float* bq = (const float*)d_in[4];
  const float* Wk = (const float*)d_in[5];
  const float* bk = (const float*)d_in[6];
  const float* Wv = (const float*)d_in[7];
  const float* bv = (const float*)d_in[8];
  const float* Wo = (const float*)d_in[9];
  const float* bo = (const float*)d_in[10];
  float* out = (float*)d_out;

  char* ws = (char*)d_ws;
  __bf16* xb    = (__bf16*)(ws + O_XB);
  __bf16* wt    = (__bf16*)(ws + O_WT);
  __bf16* qws   = (__bf16*)(ws + O_Q);
  __bf16* kws   = (__bf16*)(ws + O_K);
  __bf16* vws   = (__bf16*)(ws + O_V);
  float*  ropeC = (float*)(ws + O_RC);
  float*  ropeS = (float*)(ws + O_RS);
  __bf16* aout  = (__bf16*)(ws + O_XB);   // reuse xb region after qkv consumed it

  prep_kernel<<<4256, 256, 0, stream>>>(x, Wq, Wk, Wv, Wo, xb, wt, ropeC, ropeS);
  qkv_gemm<<<756, 256, 0, stream>>>(xb, wt, bq, bk, bv, ropeC, ropeS, qws, kws, vws);
  attn_kernel<<<dim3(25, 8, 4), 256, 0, stream>>>(qws, kws, vws, amask, aout);
  out_gemm<<<500, 256, 0, stream>>>(aout, wt + 3 * 262144, bo, out);
}